// Round 3
// 1311.927 us; speedup vs baseline: 1.2500x; 1.2500x over previous
//
#include <hip/hip_runtime.h>
#include <math.h>

// Problem constants: B=4, N=2048, C=512, H=8, D=64, 3C=1536, scale=1/8.
// d_out layout: out [4,2048,512] (4194304 f32) then attn [4,8,2048,2048].
// ws layout (f32): q[4194304] | k[4194304] | v[4194304].
// out_pre aliases q IN Q-LAYOUT [B,H,N,D] (each fused block overwrites only
// its own q rows). The rope cos/sin table lives at the START of the attn
// buffer (scratch; overwritten later by the fused kernel).

#define OFF_K 4194304
#define OFF_V 8388608

typedef float nf4 __attribute__((ext_vector_type(4)));

// XOR swizzle for transposed LDS tiles (keeps float4 groups contiguous).
#define SWZ(row, col) (((((col) >> 2) ^ (((row) >> 2) & 7)) << 2) | ((col) & 3))

// ---------------------------------------------------------------------------
// Kernel 1: qkv = x @ w_qkv, epilogue scatters into q,k,v as [B,H,N,D].
// (unchanged -- measured 132 TF/s = 84% of fp32 peak)
// ---------------------------------------------------------------------------
__global__ __launch_bounds__(256) void gemm_qkv_kernel(
    const float* __restrict__ x, const float* __restrict__ w,
    float* __restrict__ qb, float* __restrict__ kb, float* __restrict__ vb)
{
    __shared__ float As[8][132];   // [k][r]
    __shared__ float Bs[8][132];   // [k][c]
    const int tid  = threadIdx.x;
    const int row0 = blockIdx.x * 128;
    const int col0 = blockIdx.y * 128;
    const int tx = tid & 15, ty = tid >> 4;

    float acc[8][8];
    #pragma unroll
    for (int i = 0; i < 8; ++i)
        #pragma unroll
        for (int j = 0; j < 8; ++j) acc[i][j] = 0.0f;

    const int ar  = tid >> 1;          // 0..127
    const int ah  = (tid & 1) * 4;     // 0 or 4
    const int bkr = tid >> 5;          // 0..7
    const int bc  = (tid & 31) * 4;    // 0..124

    for (int k0 = 0; k0 < 512; k0 += 8) {
        float4 a4 = *(const float4*)(x + (size_t)(row0 + ar) * 512 + k0 + ah);
        float4 b4 = *(const float4*)(w + (size_t)(k0 + bkr) * 1536 + col0 + bc);
        __syncthreads();
        As[ah + 0][ar] = a4.x; As[ah + 1][ar] = a4.y;
        As[ah + 2][ar] = a4.z; As[ah + 3][ar] = a4.w;
        *(float4*)&Bs[bkr][bc] = b4;
        __syncthreads();
        #pragma unroll
        for (int kk = 0; kk < 8; ++kk) {
            float a[8], b[8];
            *(float4*)&a[0] = *(const float4*)&As[kk][ty * 8];
            *(float4*)&a[4] = *(const float4*)&As[kk][ty * 8 + 4];
            *(float4*)&b[0] = *(const float4*)&Bs[kk][tx * 8];
            *(float4*)&b[4] = *(const float4*)&Bs[kk][tx * 8 + 4];
            #pragma unroll
            for (int i = 0; i < 8; ++i)
                #pragma unroll
                for (int j = 0; j < 8; ++j)
                    acc[i][j] = fmaf(a[i], b[j], acc[i][j]);
        }
    }

    #pragma unroll
    for (int i = 0; i < 8; ++i) {
        int r  = row0 + ty * 8 + i;
        int b_ = r >> 11;
        int n  = r & 2047;
        #pragma unroll
        for (int j0 = 0; j0 < 8; j0 += 4) {
            int c     = col0 + tx * 8 + j0;
            int which = c >> 9;
            int h     = (c >> 6) & 7;
            int d     = c & 63;
            float* base = (which == 0) ? qb : ((which == 1) ? kb : vb);
            float* dst  = base + (((size_t)(b_ * 8 + h) * 2048 + n) * 64 + d);
            *(float4*)dst = make_float4(acc[i][j0], acc[i][j0 + 1],
                                        acc[i][j0 + 2], acc[i][j0 + 3]);
        }
    }
}

// ---------------------------------------------------------------------------
// Kernel 2a: cos/sin table [2048][32] as float2, fp64 math (same formula as
// the old per-element path -> bit-identical rope).
// ---------------------------------------------------------------------------
__global__ void rope_table_kernel(float2* __restrict__ tab)
{
    int idx = blockIdx.x * 256 + threadIdx.x;   // n*32 + i, 65536 total
    if (idx >= 2048 * 32) return;
    int i = idx & 31;
    int n = idx >> 5;
    double invf = pow(10000.0, -(double)(2 * i) / 64.0);
    double ang  = (double)n * invf;
    tab[idx] = make_float2((float)cos(ang), (float)sin(ang));
}

// Kernel 2b: apply rope to q and k (memory-bound now).
__global__ void rope_apply_kernel(float* __restrict__ qb, float* __restrict__ kb,
                                  const float2* __restrict__ tab)
{
    int idx = blockIdx.x * 256 + threadIdx.x;   // over B*H*N*32 = 2097152
    if (idx >= 4 * 8 * 2048 * 32) return;
    int i  = idx & 31;
    int n  = (idx >> 5) & 2047;
    int bh = idx >> 16;

    float2 cs = tab[(n << 5) | i];
    float c = cs.x, s = cs.y;

    size_t base = ((size_t)bh * 2048 + n) * 64;
    float q0 = qb[base + i], q1 = qb[base + i + 32];
    qb[base + i]      = q0 * c - q1 * s;
    qb[base + i + 32] = q1 * c + q0 * s;
    float k0 = kb[base + i], k1 = kb[base + i + 32];
    kb[base + i]      = k0 * c - k1 * s;
    kb[base + i + 32] = k1 * c + k0 * s;
}

// ---------------------------------------------------------------------------
// Kernel 3 (FUSED): per (b*h, 128-row q tile):
//  Phase 1: p~ = exp(scale*QK^T - m_run_tile) written to attn; m/l fully in
//           registers (16-lane shfl_xor reductions, rows owned by ty-group);
//           per-(row,tile) running max saved to LDS mt[128][16].
//  ctab:    mt[r][t] <- exp(mt[r][t] - m_fin) / l  (in place, reg-staged).
//  Phase 2: per 64-wide subtile: p = p~ * ctab[r][t]; nontemporal write-back;
//           stage p^T (swizzled) + V in LDS; accO += p.V (m ascending).
// LDS 74240 B -> 2 blocks/CU.
// ---------------------------------------------------------------------------
__global__ __launch_bounds__(256) void attn_scores_pv_kernel(
    const float* __restrict__ qb, const float* __restrict__ kb,
    const float* __restrict__ vb, float* __restrict__ attn,
    float* __restrict__ out_pre)
{
    __shared__ float smem[18560];
    float (*Qs)[128] = (float (*)[128])smem;            // 8192 f, phase 1
    float (*Ks)[128] = (float (*)[128])(smem + 8192);   // 8192 f, phase 1
    float (*Ps)[128] = (float (*)[128])smem;            // phase 2, aliases Qs
    float (*Vs)[68]  = (float (*)[68])(smem + 8192);    // phase 2, aliases Ks
    float (*mt)[16]  = (float (*)[16])(smem + 16384);   // 2048 f: m_tile -> ctab
    float* l_lds     = smem + 18432;                    // 128 f

    const int tid = threadIdx.x;
    const int bh  = blockIdx.x;
    const int n0  = blockIdx.y * 128;
    const int tx = tid & 15, ty = tid >> 4;

    const float* qbase = qb + ((size_t)bh * 2048 + n0) * 64;
    const float* kbase = kb + (size_t)bh * 2048 * 64;
    const float* vbase = vb + (size_t)bh * 2048 * 64;
    float* attn_base = attn + ((size_t)bh * 2048 + n0) * 2048;

    // ---------------- Phase 1 ---------------------------------------------
    // Q tile, pre-scaled by 1/8 (exact pow2 -> bit-identical GEMM).
    #pragma unroll
    for (int it = 0; it < 8; ++it) {
        int r = ty + it * 16;
        int d = tx * 4;
        float4 v4 = *(const float4*)(qbase + (size_t)r * 64 + d);
        int pc = SWZ(d, r);
        Qs[d + 0][pc] = v4.x * 0.125f; Qs[d + 1][pc] = v4.y * 0.125f;
        Qs[d + 2][pc] = v4.z * 0.125f; Qs[d + 3][pc] = v4.w * 0.125f;
    }
    float m[8], l[8];
    #pragma unroll
    for (int i = 0; i < 8; ++i) { m[i] = -3.0e38f; l[i] = 0.0f; }
    __syncthreads();

    for (int m0 = 0; m0 < 2048; m0 += 128) {
        // K tile -> regs
        float4 kv[8];
        #pragma unroll
        for (int it = 0; it < 8; ++it) {
            int c = ty + it * 16;
            kv[it] = *(const float4*)(kbase + (size_t)(m0 + c) * 64 + tx * 4);
        }
        __syncthreads();   // prior iter done reading Ks
        #pragma unroll
        for (int it = 0; it < 8; ++it) {
            int c = ty + it * 16;
            int d = tx * 4;
            int pc = SWZ(d, c);
            Ks[d + 0][pc] = kv[it].x; Ks[d + 1][pc] = kv[it].y;
            Ks[d + 2][pc] = kv[it].z; Ks[d + 3][pc] = kv[it].w;
        }
        __syncthreads();

        float acc[8][8];
        #pragma unroll
        for (int i = 0; i < 8; ++i)
            #pragma unroll
            for (int j = 0; j < 8; ++j) acc[i][j] = 0.0f;

        #pragma unroll 4
        for (int d = 0; d < 64; ++d) {
            const int sk = (d >> 2) & 7;
            float a[8], b[8];
            *(float4*)&a[0] = *(const float4*)&Qs[d][((ty * 2 + 0) ^ sk) << 2];
            *(float4*)&a[4] = *(const float4*)&Qs[d][((ty * 2 + 1) ^ sk) << 2];
            *(float4*)&b[0] = *(const float4*)&Ks[d][((tx * 2 + 0) ^ sk) << 2];
            *(float4*)&b[4] = *(const float4*)&Ks[d][((tx * 2 + 1) ^ sk) << 2];
            #pragma unroll
            for (int i = 0; i < 8; ++i)
                #pragma unroll
                for (int j = 0; j < 8; ++j)
                    acc[i][j] = fmaf(a[i], b[j], acc[i][j]);
        }

        // per-row: 16-lane shuffle reduce, reg-resident m/l, exp in place.
        #pragma unroll
        for (int i = 0; i < 8; ++i) {
            float mx = acc[i][0];
            #pragma unroll
            for (int j = 1; j < 8; ++j) mx = fmaxf(mx, acc[i][j]);
            mx = fmaxf(mx, __shfl_xor(mx, 1));
            mx = fmaxf(mx, __shfl_xor(mx, 2));
            mx = fmaxf(mx, __shfl_xor(mx, 4));
            mx = fmaxf(mx, __shfl_xor(mx, 8));
            float mn = fmaxf(m[i], mx);
            l[i] *= __expf(m[i] - mn);
            m[i]  = mn;
            float s = 0.0f;
            #pragma unroll
            for (int j = 0; j < 8; ++j) {
                acc[i][j] = __expf(acc[i][j] - mn);
                s += acc[i][j];
            }
            s += __shfl_xor(s, 1);
            s += __shfl_xor(s, 2);
            s += __shfl_xor(s, 4);
            s += __shfl_xor(s, 8);
            l[i] += s;
        }

        // write p~ = exp(s - m_run_tile)
        #pragma unroll
        for (int i = 0; i < 8; ++i) {
            int r = ty * 8 + i;
            float* drow = attn_base + (size_t)r * 2048 + m0 + tx * 8;
            *(float4*)drow       = make_float4(acc[i][0], acc[i][1], acc[i][2], acc[i][3]);
            *(float4*)(drow + 4) = make_float4(acc[i][4], acc[i][5], acc[i][6], acc[i][7]);
        }
        if (tx == 0) {
            int t = m0 >> 7;
            #pragma unroll
            for (int i = 0; i < 8; ++i) mt[ty * 8 + i][t] = m[i];
        }
    }
    if (tx == 0) {
        #pragma unroll
        for (int i = 0; i < 8; ++i) l_lds[ty * 8 + i] = l[i];
    }
    __syncthreads();

    // ctab in place: mt[r][t] = exp(mt[r][t] - m_fin) / l   (reg-staged)
    {
        int r  = tid >> 1;
        int c0 = (tid & 1) * 8;
        float v[8];
        #pragma unroll
        for (int j = 0; j < 8; ++j) v[j] = mt[r][c0 + j];
        float mf = mt[r][15];        // last running max == final max
        float lv = l_lds[r];
        __syncthreads();
        #pragma unroll
        for (int j = 0; j < 8; ++j) mt[r][c0 + j] = __expf(v[j] - mf) / lv;
    }
    __syncthreads();

    // ---------------- Phase 2: normalize + PV ------------------------------
    float accO[8][4];
    #pragma unroll
    for (int i = 0; i < 8; ++i)
        #pragma unroll
        for (int j = 0; j < 4; ++j) accO[i][j] = 0.0f;

    for (int s0 = 0; s0 < 2048; s0 += 64) {
        const int t = s0 >> 7;
        float4 vv[4];
        #pragma unroll
        for (int it = 0; it < 4; ++it)
            vv[it] = *(const float4*)(vbase + (size_t)(s0 + ty + it * 16) * 64 + tx * 4);

        float4 pp[8];
        #pragma unroll
        for (int it = 0; it < 8; ++it) {
            int r = ty + it * 16;
            float c = mt[r][t];
            float* prow = attn_base + (size_t)r * 2048 + s0 + tx * 4;
            float4 s4 = *(const float4*)prow;
            s4.x *= c; s4.y *= c; s4.z *= c; s4.w *= c;
            pp[it] = s4;
            nf4 nt = { s4.x, s4.y, s4.z, s4.w };
            __builtin_nontemporal_store(nt, (nf4*)prow);
        }

        __syncthreads();   // previous subtile's GEMM done with Ps/Vs
        #pragma unroll
        for (int it = 0; it < 4; ++it)
            *(float4*)&Vs[ty + it * 16][tx * 4] = vv[it];
        #pragma unroll
        for (int it = 0; it < 8; ++it) {
            int r = ty + it * 16;
            int mcol = tx * 4;
            int pc = SWZ(mcol, r);
            Ps[mcol + 0][pc] = pp[it].x; Ps[mcol + 1][pc] = pp[it].y;
            Ps[mcol + 2][pc] = pp[it].z; Ps[mcol + 3][pc] = pp[it].w;
        }
        __syncthreads();

        #pragma unroll 4
        for (int kk = 0; kk < 64; ++kk) {
            const int sk = (kk >> 2) & 7;
            float a[8], b[4];
            *(float4*)&a[0] = *(const float4*)&Ps[kk][((ty * 2 + 0) ^ sk) << 2];
            *(float4*)&a[4] = *(const float4*)&Ps[kk][((ty * 2 + 1) ^ sk) << 2];
            *(float4*)&b[0] = *(const float4*)&Vs[kk][tx * 4];
            #pragma unroll
            for (int i = 0; i < 8; ++i)
                #pragma unroll
                for (int j = 0; j < 4; ++j)
                    accO[i][j] = fmaf(a[i], b[j], accO[i][j]);
        }
    }

    // epilogue: out_pre in q-layout [B,H,N,D]
    #pragma unroll
    for (int i = 0; i < 8; ++i) {
        float* dst = out_pre + ((size_t)bh * 2048 + n0 + ty * 8 + i) * 64 + tx * 4;
        *(float4*)dst = make_float4(accO[i][0], accO[i][1], accO[i][2], accO[i][3]);
    }
}

// ---------------------------------------------------------------------------
// Kernel 5: out = out_pre @ w_proj + b_proj.  A in q-layout [B,H,N,D].
// Retiled 64(rows) x 128(cols) -> 512 blocks (2 blocks/CU, 2 waves/SIMD).
// ---------------------------------------------------------------------------
__global__ __launch_bounds__(256) void proj_kernel(
    const float* __restrict__ a, const float* __restrict__ w,
    const float* __restrict__ bias, float* __restrict__ out)
{
    __shared__ float As[8][68];    // [k][row], 64 rows
    __shared__ float Bs[8][132];   // [k][col], 128 cols
    const int tid  = threadIdx.x;
    const int row0 = blockIdx.x * 64;
    const int col0 = blockIdx.y * 128;
    const int tx = tid & 31, ty = tid >> 5;   // tx: col-group(4), ty: row-group(8)

    float acc[8][4];
    #pragma unroll
    for (int i = 0; i < 8; ++i)
        #pragma unroll
        for (int j = 0; j < 4; ++j) acc[i][j] = 0.0f;

    const int ar  = tid >> 1;         // 0..63 for tid<128
    const int ah  = (tid & 1) * 4;
    const int bkr = tid >> 5;         // 0..7
    const int bc  = (tid & 31) * 4;

    const int r_  = row0 + ar;
    const int b_  = r_ >> 11;
    const int n_  = r_ & 2047;

    for (int k0 = 0; k0 < 512; k0 += 8) {
        float4 a4;
        if (tid < 128) {
            const int kk_ = k0 + ah;
            const int h_  = kk_ >> 6;
            const int d_  = kk_ & 63;
            a4 = *(const float4*)(a + (((size_t)(b_ * 8 + h_) * 2048 + n_) * 64 + d_));
        }
        float4 b4 = *(const float4*)(w + (size_t)(k0 + bkr) * 512 + col0 + bc);
        __syncthreads();
        if (tid < 128) {
            As[ah + 0][ar] = a4.x; As[ah + 1][ar] = a4.y;
            As[ah + 2][ar] = a4.z; As[ah + 3][ar] = a4.w;
        }
        *(float4*)&Bs[bkr][bc] = b4;
        __syncthreads();
        #pragma unroll
        for (int kk = 0; kk < 8; ++kk) {
            float av[8], bv[4];
            *(float4*)&av[0] = *(const float4*)&As[kk][ty * 8];
            *(float4*)&av[4] = *(const float4*)&As[kk][ty * 8 + 4];
            *(float4*)&bv[0] = *(const float4*)&Bs[kk][tx * 4];
            #pragma unroll
            for (int i = 0; i < 8; ++i)
                #pragma unroll
                for (int j = 0; j < 4; ++j)
                    acc[i][j] = fmaf(av[i], bv[j], acc[i][j]);
        }
    }

    float bj[4];
    #pragma unroll
    for (int j = 0; j < 4; ++j) bj[j] = bias[col0 + tx * 4 + j];

    #pragma unroll
    for (int i = 0; i < 8; ++i) {
        int r = row0 + ty * 8 + i;
        float* dst = out + (size_t)r * 512 + col0 + tx * 4;
        *(float4*)dst = make_float4(acc[i][0] + bj[0], acc[i][1] + bj[1],
                                    acc[i][2] + bj[2], acc[i][3] + bj[3]);
    }
}

// ---------------------------------------------------------------------------
extern "C" void kernel_launch(void* const* d_in, const int* in_sizes, int n_in,
                              void* d_out, int out_size, void* d_ws, size_t ws_size,
                              hipStream_t stream)
{
    const float* x      = (const float*)d_in[0];
    const float* w_qkv  = (const float*)d_in[1];
    const float* w_proj = (const float*)d_in[2];
    const float* b_proj = (const float*)d_in[3];

    float* out  = (float*)d_out;                 // [4,2048,512]
    float* attn = (float*)d_out + 4194304;       // [4,8,2048,2048]

    float* ws = (float*)d_ws;
    float* q = ws;                // [B,H,N,D]
    float* k = ws + OFF_K;
    float* v = ws + OFF_V;
    float* out_pre = ws;          // aliases q in q-layout (self-owned rows)

    // rope table scratch: start of attn buffer (overwritten later)
    float2* rope_tab = (float2*)attn;

    gemm_qkv_kernel<<<dim3(64, 12), 256, 0, stream>>>(x, w_qkv, q, k, v);
    rope_table_kernel<<<256, 256, 0, stream>>>(rope_tab);
    rope_apply_kernel<<<8192, 256, 0, stream>>>(q, k, rope_tab);
    attn_scores_pv_kernel<<<dim3(32, 16), 256, 0, stream>>>(q, k, v, attn, out_pre);
    proj_kernel<<<dim3(128, 4), 256, 0, stream>>>(out_pre, w_proj, b_proj, out);
}